// Round 1
// baseline (7838.139 us; speedup 1.0000x reference)
//
#include <hip/hip_runtime.h>
#include <stdint.h>

#define KT 500
#define KH 1024
#define KG 2048

typedef short bf16x8 __attribute__((ext_vector_type(8)));
typedef float f32x4 __attribute__((ext_vector_type(4)));

__device__ __forceinline__ unsigned short f2bf(float f){
  union { float f; unsigned int i; } u; u.f = f;
  unsigned int x = u.i;
  return (unsigned short)((x + 0x7fffu + ((x >> 16) & 1u)) >> 16);
}
__device__ __forceinline__ float bf2f(unsigned short h){
  union { unsigned int i; float f; } u; u.i = ((unsigned int)h) << 16;
  return u.f;
}

// ---------------- cast fp32 -> bf16 (vectorized) ----------------
__global__ __launch_bounds__(256) void castk(const float* __restrict__ s,
                                             unsigned short* __restrict__ d, int n4){
  int i = blockIdx.x*256 + threadIdx.x;
  if (i >= n4) return;
  float4 v = ((const float4*)s)[i];
  unsigned int lo = (unsigned int)f2bf(v.x) | ((unsigned int)f2bf(v.y) << 16);
  unsigned int hi = (unsigned int)f2bf(v.z) | ((unsigned int)f2bf(v.w) << 16);
  ((uint2*)d)[i] = make_uint2(lo, hi);
}

// ---------------- 128x128 bf16 MFMA GEMM, x2/hcat indexing folded into A gather ---------
// MODE 0: A = xb [16][500][512], rows (s,t): s<16 -> x[s][t], s>=16 -> x[s-16][499-t]
// MODE 1: A = hs0 [32][500][1024] bf16; x2_1[s,t,f] per reference concat/reversal
template<int MODE, int KDIM>
__global__ __launch_bounds__(256) void gemm_bn(
    const unsigned short* __restrict__ A,
    const unsigned short* __restrict__ Bw,   // [2048][KDIM] bf16 (gate-major)
    unsigned short* __restrict__ Wout)       // [16000][2048] bf16
{
  __shared__ __attribute__((aligned(16))) unsigned short As[128*72]; // +8 pad breaks bank conflicts
  __shared__ __attribute__((aligned(16))) unsigned short Bs[128*72];
  const int tid = threadIdx.x;
  const int lane = tid & 63, wid = tid >> 6;
  const int ntile = blockIdx.x, mtile = blockIdx.y;
  const int arow_loc = tid >> 3;   // 0..31
  const int k8 = tid & 7;

  long abaseLo[4], abaseHi[4], bbase[4];
  #pragma unroll
  for (int i = 0; i < 4; i++){
    int r = mtile*128 + i*32 + arow_loc;
    int s = r / KT;
    int t = r - s*KT;
    if (MODE == 0){
      abaseLo[i] = (s < 16) ? (long)((s*KT + t)*512)
                            : (long)(((s-16)*KT + (KT-1-t))*512);
      abaseHi[i] = 0;
    } else {
      int sp = s & 15;
      int rev = (s >= 16);
      abaseLo[i] = (long)((sp*KT + (rev ? KT-1-t : t)) * KH);        // f < 1024
      abaseHi[i] = (long)(((16+sp)*KT + (rev ? t : KT-1-t)) * KH);   // f >= 1024
    }
    bbase[i] = (long)(ntile*128 + i*32 + arow_loc) * KDIM;
  }

  f32x4 acc[4][4];
  #pragma unroll
  for (int a=0;a<4;a++)
    #pragma unroll
    for (int b=0;b<4;b++)
      acc[a][b] = (f32x4){0.f,0.f,0.f,0.f};

  const int mhalf = wid & 1, nhalf = wid >> 1;
  const int lrow = lane & 15, quad = lane >> 4;

  for (int k0 = 0; k0 < KDIM; k0 += 64){
    const int kel = k0 + k8*8;
    #pragma unroll
    for (int i = 0; i < 4; i++){
      long aoff;
      if (MODE == 0) aoff = abaseLo[i] + kel;
      else           aoff = (kel < KH) ? (abaseLo[i] + kel) : (abaseHi[i] + (kel - KH));
      uint4 va = *(const uint4*)(A + aoff);
      uint4 vb = *(const uint4*)(Bw + bbase[i] + kel);
      *(uint4*)&As[(i*32 + arow_loc)*72 + k8*8] = va;
      *(uint4*)&Bs[(i*32 + arow_loc)*72 + k8*8] = vb;
    }
    __syncthreads();
    #pragma unroll
    for (int kk = 0; kk < 64; kk += 32){
      bf16x8 af[4], bfr[4];
      #pragma unroll
      for (int mt=0; mt<4; mt++)
        af[mt] = *(const bf16x8*)&As[(mhalf*64 + mt*16 + lrow)*72 + kk + quad*8];
      #pragma unroll
      for (int nt=0; nt<4; nt++)
        bfr[nt] = *(const bf16x8*)&Bs[(nhalf*64 + nt*16 + lrow)*72 + kk + quad*8];
      #pragma unroll
      for (int mt=0; mt<4; mt++)
        #pragma unroll
        for (int nt=0; nt<4; nt++)
          acc[mt][nt] = __builtin_amdgcn_mfma_f32_16x16x32_bf16(af[mt], bfr[nt], acc[mt][nt], 0, 0, 0);
    }
    __syncthreads();
  }

  // C/D layout: col = lane&15, row = quad*4 + reg (m89-verified)
  #pragma unroll
  for (int mt=0; mt<4; mt++)
    #pragma unroll
    for (int nt=0; nt<4; nt++)
      #pragma unroll
      for (int r=0; r<4; r++){
        int grow = mtile*128 + mhalf*64 + mt*16 + quad*4 + r;
        int gcol = ntile*128 + nhalf*64 + nt*16 + lrow;
        Wout[(long)grow*KG + gcol] = f2bf(acc[mt][nt][r]);
      }
}

// ---------------- batchnorm stats: partial sums then finalize ----------------
__global__ __launch_bounds__(256) void bn_partial(const unsigned short* __restrict__ W,
                                                  float* __restrict__ part){
  const int blk = blockIdx.x, tid = threadIdx.x;   // 125 blocks x 128 rows
  const int c0 = tid*8;
  float s[8], qq[8];
  #pragma unroll
  for (int j=0;j<8;j++){ s[j]=0.f; qq[j]=0.f; }
  const unsigned short* base = W + (long)blk*128*KG + c0;
  for (int r=0;r<128;r++){
    uint4 v = *(const uint4*)(base + (long)r*KG);
    unsigned int w[4] = {v.x, v.y, v.z, v.w};
    #pragma unroll
    for (int p=0;p<4;p++){
      union { unsigned int i; float f; } lo, hi;
      lo.i = w[p] << 16;
      hi.i = w[p] & 0xffff0000u;
      s[2*p]   += lo.f; qq[2*p]   += lo.f*lo.f;
      s[2*p+1] += hi.f; qq[2*p+1] += hi.f*hi.f;
    }
  }
  float* pd = part + (long)blk*4096;
  #pragma unroll
  for (int j=0;j<8;j++){ pd[c0+j] = s[j]; pd[KG + c0 + j] = qq[j]; }
}

__global__ __launch_bounds__(256) void bn_final(const float* __restrict__ part,
                                                const float* __restrict__ gamma,
                                                const float* __restrict__ beta,
                                                float* __restrict__ scsh){
  int g = blockIdx.x*256 + threadIdx.x;   // 2048
  float s=0.f, qq=0.f;
  for (int b=0;b<125;b++){ s += part[(long)b*4096 + g]; qq += part[(long)b*4096 + KG + g]; }
  float mean = s * (1.f/16000.f);
  float var  = qq * (1.f/16000.f) - mean*mean;
  float sc = gamma[g] * rsqrtf(var + 1e-5f);
  scsh[g]      = sc;                       // scale
  scsh[KG + g] = beta[g] - mean*sc;        // shift
}

// ---------------- persistent recurrence: 64 blocks, U pinned in LDS ----------------
// Block q owns a-gates [16q,16q+16) and z-gates [1024+16q, ...), i.e. h columns [16q,16q+16).
// Cross-block h exchange through global bf16 ping-pong + per-producer flags,
// agent-scope fences for cross-XCD L2 visibility. fp32 state kept in LDS (no bf16 drift in state).
template<int LAYER>
__global__ __launch_bounds__(256) void recur(
    const unsigned short* __restrict__ Ub,     // [2048][1024] bf16
    const unsigned short* __restrict__ Wn,     // [32][500][2048] bf16 (un-normalized)
    const float* __restrict__ scsh,            // [2][2048]
    unsigned short* __restrict__ hbuf,         // [2][32][1024] bf16 ping-pong (pre-zeroed)
    int* __restrict__ flags,                   // [500][64] (pre-zeroed)
    unsigned short* __restrict__ hsOut,        // LAYER 0: [32][500][1024] bf16
    float* __restrict__ out)                   // LAYER 1: [16][500][2048] fp32
{
  __shared__ __attribute__((aligned(16))) unsigned short Ush[32*1032]; // +8 pad per row
  __shared__ __attribute__((aligned(16))) unsigned short hsh[32*1032];
  __shared__ float gA[512];
  __shared__ float gZ[512];
  __shared__ float hown[512];
  __shared__ float scA[16], shA[16], scZ[16], shZ[16];

  const int tid = threadIdx.x;
  const int q = blockIdx.x;
  const int ga = q*16;

  // load U slice (rows 0-15 = a-gates, 16-31 = z-gates)
  #pragma unroll
  for (int i=0;i<16;i++){
    int c = i*256 + tid;
    int row = c >> 7, k8c = c & 127;
    int grow = (row < 16) ? (ga + row) : (KH + ga + row - 16);
    uint4 v = *(const uint4*)(Ub + (long)grow*KH + k8c*8);
    *(uint4*)&Ush[row*1032 + k8c*8] = v;
  }
  if (tid < 64){
    int j = tid & 15, w = tid >> 4;
    if      (w==0) scA[j] = scsh[ga+j];
    else if (w==1) shA[j] = scsh[KG + ga + j];
    else if (w==2) scZ[j] = scsh[KH + ga + j];
    else           shZ[j] = scsh[KG + KH + ga + j];
  }
  hown[tid] = 0.f; hown[tid+256] = 0.f;
  __syncthreads();

  const int lane = tid & 63, wid = tid >> 6;
  const int lrow = lane & 15, quad = lane >> 4;
  const int mhalf = wid & 1, ghalf = wid >> 1;   // wave -> (s-half, a/z-half)
  const int s0 = tid >> 4, j0 = tid & 15;        // epilogue pair mapping

  for (int t = 0; t < KT; t++){
    // prefetch w(t) (independent of h) so its latency hides under the flag poll
    const unsigned short* wr0 = Wn + (long)(s0*KT + t)*KG;
    const unsigned short* wr1 = Wn + (long)((s0+16)*KT + t)*KG;
    unsigned short wa0 = wr0[ga + j0];
    unsigned short wz0 = wr0[KH + ga + j0];
    unsigned short wa1 = wr1[ga + j0];
    unsigned short wz1 = wr1[KH + ga + j0];
    asm volatile("" ::: "memory");  // keep prefetch issued before the poll

    if (t > 0 && tid < 64){
      while (__hip_atomic_load(&flags[(t-1)*64 + tid], __ATOMIC_RELAXED,
                               __HIP_MEMORY_SCOPE_AGENT) == 0){}
    }
    __syncthreads();
    __builtin_amdgcn_fence(__ATOMIC_ACQUIRE, "agent");  // invalidate stale L1/L2

    // stage h(t) -> LDS
    const unsigned short* hb = hbuf + (t & 1)*32768;
    #pragma unroll
    for (int i=0;i<16;i++){
      int c = i*256 + tid;
      int row = c >> 7, k8c = c & 127;
      uint4 v = *(const uint4*)(hb + row*KH + k8c*8);
      *(uint4*)&hsh[row*1032 + k8c*8] = v;
    }
    __syncthreads();

    // gates = h @ U_slice^T : each wave one 16x16 tile, K=1024
    f32x4 acc = (f32x4){0.f,0.f,0.f,0.f};
    const unsigned short* ar = &hsh[(mhalf*16 + lrow)*1032 + quad*8];
    const unsigned short* br = &Ush[(ghalf*16 + lrow)*1032 + quad*8];
    #pragma unroll
    for (int k0=0;k0<KH;k0+=32){
      bf16x8 af  = *(const bf16x8*)(ar + k0);
      bf16x8 bfr = *(const bf16x8*)(br + k0);
      acc = __builtin_amdgcn_mfma_f32_16x16x32_bf16(af, bfr, acc, 0,0,0);
    }
    float* gd = ghalf ? gZ : gA;
    #pragma unroll
    for (int r=0;r<4;r++)
      gd[(mhalf*16 + quad*4 + r)*16 + lrow] = acc[r];
    __syncthreads();

    // epilogue: 2 (s,j) pairs per thread; fp32 state in hown
    float hn0, hn1;
    {
      float a  = gA[s0*16 + j0] + bf2f(wa0)*scA[j0] + shA[j0];
      float zp = gZ[s0*16 + j0] + bf2f(wz0)*scZ[j0] + shZ[j0];
      float z = 1.f/(1.f + __expf(-zp));
      float hp = hown[s0*16 + j0];
      hn0 = z*hp + (1.f - z)*fmaxf(a, 0.f);
      hown[s0*16 + j0] = hn0;
    }
    {
      int s1 = s0 + 16;
      float a  = gA[s1*16 + j0] + bf2f(wa1)*scA[j0] + shA[j0];
      float zp = gZ[s1*16 + j0] + bf2f(wz1)*scZ[j0] + shZ[j0];
      float z = 1.f/(1.f + __expf(-zp));
      float hp = hown[s1*16 + j0];
      hn1 = z*hp + (1.f - z)*fmaxf(a, 0.f);
      hown[s1*16 + j0] = hn1;
    }
    unsigned short hb0 = f2bf(hn0), hb1 = f2bf(hn1);
    unsigned short* hw = hbuf + ((t+1)&1)*32768;
    hw[(long)s0*KH + ga + j0]      = hb0;
    hw[(long)(s0+16)*KH + ga + j0] = hb1;
    if (LAYER == 0){
      hsOut[(long)(s0*KT + t)*KH + ga + j0]        = hb0;
      hsOut[(long)((s0+16)*KT + t)*KH + ga + j0]   = hb1;
    } else {
      out[(long)(s0*KT + t)*KG + ga + j0]                 = hn0;  // forward half
      out[(long)(s0*KT + (KT-1-t))*KG + KH + ga + j0]     = hn1;  // backward half, reversed
    }
    __syncthreads();  // drains all stores (vmcnt 0 before s_barrier)
    if (tid == 0){
      __builtin_amdgcn_fence(__ATOMIC_RELEASE, "agent"); // L2 writeback to coherence point
      __hip_atomic_store(&flags[t*64 + q], 1, __ATOMIC_RELAXED, __HIP_MEMORY_SCOPE_AGENT);
    }
  }
}

// ---------------- orchestration ----------------
extern "C" void kernel_launch(void* const* d_in, const int* in_sizes, int n_in,
                              void* d_out, int out_size, void* d_ws, size_t ws_size,
                              hipStream_t stream)
{
  const float* x  = (const float*)d_in[0];
  const float* w0 = (const float*)d_in[1];
  const float* u0 = (const float*)d_in[2];
  const float* g0 = (const float*)d_in[3];
  const float* b0 = (const float*)d_in[4];
  const float* w1 = (const float*)d_in[5];
  const float* u1 = (const float*)d_in[6];
  const float* g1 = (const float*)d_in[7];
  const float* b1 = (const float*)d_in[8];
  float* out = (float*)d_out;

  char* p = (char*)d_ws;
  auto alloc = [&](size_t n){ char* r = p; p += (n + 255) & ~(size_t)255; return r; };
  unsigned short* xb   = (unsigned short*)alloc((size_t)16*KT*512*2);
  unsigned short* w0b  = (unsigned short*)alloc((size_t)KG*512*2);
  unsigned short* u0b  = (unsigned short*)alloc((size_t)KG*KH*2);
  unsigned short* w1b  = (unsigned short*)alloc((size_t)KG*KG*2);
  unsigned short* u1b  = (unsigned short*)alloc((size_t)KG*KH*2);
  unsigned short* wbuf = (unsigned short*)alloc((size_t)32*KT*KG*2);   // 65.5 MB
  unsigned short* hs0  = (unsigned short*)alloc((size_t)32*KT*KH*2);   // 32.8 MB
  float* part          = (float*)alloc((size_t)125*4096*4);
  float* scsh          = (float*)alloc((size_t)2*KG*4);
  unsigned short* hbuf = (unsigned short*)alloc((size_t)2*2*32*KH*2);
  int* flags           = (int*)alloc((size_t)2*KT*64*4);

  auto cast = [&](const float* s, unsigned short* d, int n){
    int n4 = n >> 2;
    castk<<<(n4+255)/256, 256, 0, stream>>>(s, d, n4);
  };
  cast(x,  xb,  16*KT*512);
  cast(w0, w0b, KG*512);
  cast(u0, u0b, KG*KH);
  cast(w1, w1b, KG*KG);
  cast(u1, u1b, KG*KH);
  hipMemsetAsync(hbuf,  0, (size_t)2*2*32*KH*2, stream);
  hipMemsetAsync(flags, 0, (size_t)2*KT*64*4,  stream);

  // layer 0
  gemm_bn<0,512><<<dim3(16,125), 256, 0, stream>>>(xb, w0b, wbuf);
  bn_partial<<<125,256,0,stream>>>(wbuf, part);
  bn_final<<<8,256,0,stream>>>(part, g0, b0, scsh);
  recur<0><<<64,256,0,stream>>>(u0b, wbuf, scsh, hbuf, flags, hs0, (float*)nullptr);

  // layer 1
  gemm_bn<1,2048><<<dim3(16,125), 256, 0, stream>>>(hs0, w1b, wbuf);
  bn_partial<<<125,256,0,stream>>>(wbuf, part);
  bn_final<<<8,256,0,stream>>>(part, g1, b1, scsh);
  recur<1><<<64,256,0,stream>>>(u1b, wbuf, scsh, hbuf + 2*32*KH, flags + KT*64,
                                (unsigned short*)nullptr, out);
}

// Round 2
// 4570.291 us; speedup vs baseline: 1.7150x; 1.7150x over previous
//
#include <hip/hip_runtime.h>
#include <stdint.h>

#define KT 500
#define KH 1024
#define KG 2048

typedef short bf16x8 __attribute__((ext_vector_type(8)));
typedef float f32x4 __attribute__((ext_vector_type(4)));

__device__ __forceinline__ unsigned short f2bf(float f){
  union { float f; unsigned int i; } u; u.f = f;
  unsigned int x = u.i;
  return (unsigned short)((x + 0x7fffu + ((x >> 16) & 1u)) >> 16);
}
__device__ __forceinline__ float bf2f(unsigned short h){
  union { unsigned int i; float f; } u; u.i = ((unsigned int)h) << 16;
  return u.f;
}

// device-scope (agent) 16B load / 4B store: sc1 => served at MALL coherence
// point, bypasses the non-coherent per-XCD L2. No cache-wide fences needed.
__device__ __forceinline__ void load_b128_dev(uint4& dst, const void* p){
  asm volatile("global_load_dwordx4 %0, %1, off sc1"
               : "=v"(dst) : "v"(p) : "memory");
}
__device__ __forceinline__ void store_b32_dev(void* p, unsigned int v){
  asm volatile("global_store_dword %0, %1, off sc1"
               :: "v"(p), "v"(v) : "memory");
}
__device__ __forceinline__ void wait_vm0(){
  asm volatile("s_waitcnt vmcnt(0)" ::: "memory");
}

// ---------------- cast fp32 -> bf16 (vectorized) ----------------
__global__ __launch_bounds__(256) void castk(const float* __restrict__ s,
                                             unsigned short* __restrict__ d, int n4){
  int i = blockIdx.x*256 + threadIdx.x;
  if (i >= n4) return;
  float4 v = ((const float4*)s)[i];
  unsigned int lo = (unsigned int)f2bf(v.x) | ((unsigned int)f2bf(v.y) << 16);
  unsigned int hi = (unsigned int)f2bf(v.z) | ((unsigned int)f2bf(v.w) << 16);
  ((uint2*)d)[i] = make_uint2(lo, hi);
}

// ---------------- 128x128 bf16 MFMA GEMM, x2/hcat indexing folded into A gather ---------
template<int MODE, int KDIM>
__global__ __launch_bounds__(256) void gemm_bn(
    const unsigned short* __restrict__ A,
    const unsigned short* __restrict__ Bw,   // [2048][KDIM] bf16 (gate-major)
    unsigned short* __restrict__ Wout)       // [16000][2048] bf16
{
  __shared__ __attribute__((aligned(16))) unsigned short As[128*72];
  __shared__ __attribute__((aligned(16))) unsigned short Bs[128*72];
  const int tid = threadIdx.x;
  const int lane = tid & 63, wid = tid >> 6;
  const int ntile = blockIdx.x, mtile = blockIdx.y;
  const int arow_loc = tid >> 3;   // 0..31
  const int k8 = tid & 7;

  long abaseLo[4], abaseHi[4], bbase[4];
  #pragma unroll
  for (int i = 0; i < 4; i++){
    int r = mtile*128 + i*32 + arow_loc;
    int s = r / KT;
    int t = r - s*KT;
    if (MODE == 0){
      abaseLo[i] = (s < 16) ? (long)((s*KT + t)*512)
                            : (long)(((s-16)*KT + (KT-1-t))*512);
      abaseHi[i] = 0;
    } else {
      int sp = s & 15;
      int rev = (s >= 16);
      abaseLo[i] = (long)((sp*KT + (rev ? KT-1-t : t)) * KH);
      abaseHi[i] = (long)(((16+sp)*KT + (rev ? t : KT-1-t)) * KH);
    }
    bbase[i] = (long)(ntile*128 + i*32 + arow_loc) * KDIM;
  }

  f32x4 acc[4][4];
  #pragma unroll
  for (int a=0;a<4;a++)
    #pragma unroll
    for (int b=0;b<4;b++)
      acc[a][b] = (f32x4){0.f,0.f,0.f,0.f};

  const int mhalf = wid & 1, nhalf = wid >> 1;
  const int lrow = lane & 15, quad = lane >> 4;

  for (int k0 = 0; k0 < KDIM; k0 += 64){
    const int kel = k0 + k8*8;
    #pragma unroll
    for (int i = 0; i < 4; i++){
      long aoff;
      if (MODE == 0) aoff = abaseLo[i] + kel;
      else           aoff = (kel < KH) ? (abaseLo[i] + kel) : (abaseHi[i] + (kel - KH));
      uint4 va = *(const uint4*)(A + aoff);
      uint4 vb = *(const uint4*)(Bw + bbase[i] + kel);
      *(uint4*)&As[(i*32 + arow_loc)*72 + k8*8] = va;
      *(uint4*)&Bs[(i*32 + arow_loc)*72 + k8*8] = vb;
    }
    __syncthreads();
    #pragma unroll
    for (int kk = 0; kk < 64; kk += 32){
      bf16x8 af[4], bfr[4];
      #pragma unroll
      for (int mt=0; mt<4; mt++)
        af[mt] = *(const bf16x8*)&As[(mhalf*64 + mt*16 + lrow)*72 + kk + quad*8];
      #pragma unroll
      for (int nt=0; nt<4; nt++)
        bfr[nt] = *(const bf16x8*)&Bs[(nhalf*64 + nt*16 + lrow)*72 + kk + quad*8];
      #pragma unroll
      for (int mt=0; mt<4; mt++)
        #pragma unroll
        for (int nt=0; nt<4; nt++)
          acc[mt][nt] = __builtin_amdgcn_mfma_f32_16x16x32_bf16(af[mt], bfr[nt], acc[mt][nt], 0, 0, 0);
    }
    __syncthreads();
  }

  #pragma unroll
  for (int mt=0; mt<4; mt++)
    #pragma unroll
    for (int nt=0; nt<4; nt++)
      #pragma unroll
      for (int r=0; r<4; r++){
        int grow = mtile*128 + mhalf*64 + mt*16 + quad*4 + r;
        int gcol = ntile*128 + nhalf*64 + nt*16 + lrow;
        Wout[(long)grow*KG + gcol] = f2bf(acc[mt][nt][r]);
      }
}

// ---------------- batchnorm stats ----------------
__global__ __launch_bounds__(256) void bn_partial(const unsigned short* __restrict__ W,
                                                  float* __restrict__ part){
  const int blk = blockIdx.x, tid = threadIdx.x;
  const int c0 = tid*8;
  float s[8], qq[8];
  #pragma unroll
  for (int j=0;j<8;j++){ s[j]=0.f; qq[j]=0.f; }
  const unsigned short* base = W + (long)blk*128*KG + c0;
  for (int r=0;r<128;r++){
    uint4 v = *(const uint4*)(base + (long)r*KG);
    unsigned int w[4] = {v.x, v.y, v.z, v.w};
    #pragma unroll
    for (int p=0;p<4;p++){
      union { unsigned int i; float f; } lo, hi;
      lo.i = w[p] << 16;
      hi.i = w[p] & 0xffff0000u;
      s[2*p]   += lo.f; qq[2*p]   += lo.f*lo.f;
      s[2*p+1] += hi.f; qq[2*p+1] += hi.f*hi.f;
    }
  }
  float* pd = part + (long)blk*4096;
  #pragma unroll
  for (int j=0;j<8;j++){ pd[c0+j] = s[j]; pd[KG + c0 + j] = qq[j]; }
}

__global__ __launch_bounds__(256) void bn_final(const float* __restrict__ part,
                                                const float* __restrict__ gamma,
                                                const float* __restrict__ beta,
                                                float* __restrict__ scsh){
  int g = blockIdx.x*256 + threadIdx.x;
  float s=0.f, qq=0.f;
  for (int b=0;b<125;b++){ s += part[(long)b*4096 + g]; qq += part[(long)b*4096 + KG + g]; }
  float mean = s * (1.f/16000.f);
  float var  = qq * (1.f/16000.f) - mean*mean;
  float sc = gamma[g] * rsqrtf(var + 1e-5f);
  scsh[g]      = sc;
  scsh[KG + g] = beta[g] - mean*sc;
}

// ---------------- persistent recurrence ----------------
// Block q owns h columns [16q,16q+16). h exchange via sc1 (device-scope) loads/
// stores to a global ping-pong at the MALL coherence point + per-producer flags.
// No cache-wide fences: Wn/U stay L2/LDS-resident across steps.
template<int LAYER>
__global__ __launch_bounds__(256, 1) void recur(
    const unsigned short* __restrict__ Ub,     // [2048][1024] bf16
    const unsigned short* __restrict__ Wn,     // [32][500][2048] bf16 (un-normalized)
    const float* __restrict__ scsh,            // [2][2048]
    unsigned short* __restrict__ hbuf,         // [2][32][1024] bf16 ping-pong (pre-zeroed)
    int* __restrict__ flags,                   // [500][64] (pre-zeroed)
    unsigned short* __restrict__ hsOut,        // LAYER 0: [32][500][1024] bf16
    float* __restrict__ out)                   // LAYER 1: [16][500][2048] fp32
{
  __shared__ __attribute__((aligned(16))) unsigned short Ush[32*1032];
  __shared__ __attribute__((aligned(16))) unsigned short hsh[32*1032];
  __shared__ float gA[32*20];   // stride 20: 2-way bank alias only (free)
  __shared__ float gZ[32*20];
  __shared__ float hown[512];
  __shared__ float scA[16], shA[16], scZ[16], shZ[16];

  const int tid = threadIdx.x;
  const int q = blockIdx.x;
  const int ga = q*16;

  // load U slice (rows 0-15 = a-gates, 16-31 = z-gates)
  #pragma unroll
  for (int i=0;i<16;i++){
    int c = i*256 + tid;
    int row = c >> 7, k8c = c & 127;
    int grow = (row < 16) ? (ga + row) : (KH + ga + row - 16);
    uint4 v = *(const uint4*)(Ub + (long)grow*KH + k8c*8);
    *(uint4*)&Ush[row*1032 + k8c*8] = v;
  }
  if (tid < 64){
    int j = tid & 15, w = tid >> 4;
    if      (w==0) scA[j] = scsh[ga+j];
    else if (w==1) shA[j] = scsh[KG + ga + j];
    else if (w==2) scZ[j] = scsh[KH + ga + j];
    else           shZ[j] = scsh[KG + KH + ga + j];
  }
  hown[tid] = 0.f; hown[tid+256] = 0.f;
  __syncthreads();

  const int lane = tid & 63, wid = tid >> 6;
  const int lrow = lane & 15, quad = lane >> 4;
  const int mhalf = wid & 1, ghalf = wid >> 1;
  // epilogue mapping: thread -> (row s, adjacent col pair 2p,2p+1)
  const int es = tid >> 3, ep = tid & 7;
  // staging mapping
  const int r0 = tid >> 7, kc = tid & 127;

  for (int t = 0; t < KT; t++){
    // prefetch w(t) (independent of h) under the flag poll; normal cached loads
    const unsigned short* wr = Wn + (long)(es*KT + t)*KG + ga + 2*ep;
    unsigned int wa01 = *(const unsigned int*)(wr);
    unsigned int wz01 = *(const unsigned int*)(wr + KH);
    asm volatile("" ::: "memory");

    if (t > 0 && tid < 64){
      while (__hip_atomic_load(&flags[(t-1)*64 + tid], __ATOMIC_RELAXED,
                               __HIP_MEMORY_SCOPE_AGENT) == 0){}
    }
    __syncthreads();                                   // B1: all flags seen

    // stage h(t) -> LDS via device-scope 16B loads (reads MALL, not stale L2)
    const unsigned short* hb = hbuf + (t & 1)*32768 + r0*KH + kc*8;
    uint4 hreg[16];
    #pragma unroll
    for (int i=0;i<16;i++)
      load_b128_dev(hreg[i], hb + i*2048);
    wait_vm0();
    #pragma unroll
    for (int i=0;i<16;i++)
      *(uint4*)&hsh[(2*i + r0)*1032 + kc*8] = hreg[i];
    __syncthreads();                                   // B2: h staged

    // gates = h @ U_slice^T : each wave one 16x16 tile, K=1024, 4 indep accs
    f32x4 a0 = (f32x4){0,0,0,0}, a1 = a0, a2 = a0, a3 = a0;
    const unsigned short* ar = &hsh[(mhalf*16 + lrow)*1032 + quad*8];
    const unsigned short* br = &Ush[(ghalf*16 + lrow)*1032 + quad*8];
    #pragma unroll
    for (int k0=0;k0<KH;k0+=128){
      a0 = __builtin_amdgcn_mfma_f32_16x16x32_bf16(*(const bf16x8*)(ar+k0),    *(const bf16x8*)(br+k0),    a0,0,0,0);
      a1 = __builtin_amdgcn_mfma_f32_16x16x32_bf16(*(const bf16x8*)(ar+k0+32), *(const bf16x8*)(br+k0+32), a1,0,0,0);
      a2 = __builtin_amdgcn_mfma_f32_16x16x32_bf16(*(const bf16x8*)(ar+k0+64), *(const bf16x8*)(br+k0+64), a2,0,0,0);
      a3 = __builtin_amdgcn_mfma_f32_16x16x32_bf16(*(const bf16x8*)(ar+k0+96), *(const bf16x8*)(br+k0+96), a3,0,0,0);
    }
    f32x4 accs = (a0 + a1) + (a2 + a3);
    float* gd = ghalf ? gZ : gA;
    #pragma unroll
    for (int r=0;r<4;r++)
      gd[(mhalf*16 + quad*4 + r)*20 + lrow] = accs[r];
    __syncthreads();                                   // B3: gates ready

    // epilogue: one row, two adjacent cols per thread
    float2 gav = *(const float2*)&gA[es*20 + 2*ep];
    float2 gzv = *(const float2*)&gZ[es*20 + 2*ep];
    float2 hpv = *(const float2*)&hown[es*16 + 2*ep];
    float2 scav = *(const float2*)&scA[2*ep];
    float2 shav = *(const float2*)&shA[2*ep];
    float2 sczv = *(const float2*)&scZ[2*ep];
    float2 shzv = *(const float2*)&shZ[2*ep];
    float aa0 = gav.x + bf2f((unsigned short)(wa01 & 0xffff)) * scav.x + shav.x;
    float aa1 = gav.y + bf2f((unsigned short)(wa01 >> 16))    * scav.y + shav.y;
    float zz0 = gzv.x + bf2f((unsigned short)(wz01 & 0xffff)) * sczv.x + shzv.x;
    float zz1 = gzv.y + bf2f((unsigned short)(wz01 >> 16))    * sczv.y + shzv.y;
    float z0 = 1.f/(1.f + __expf(-zz0));
    float z1 = 1.f/(1.f + __expf(-zz1));
    float hn0 = z0*hpv.x + (1.f - z0)*fmaxf(aa0, 0.f);
    float hn1 = z1*hpv.y + (1.f - z1)*fmaxf(aa1, 0.f);
    *(float2*)&hown[es*16 + 2*ep] = make_float2(hn0, hn1);

    unsigned int hpack = (unsigned int)f2bf(hn0) | ((unsigned int)f2bf(hn1) << 16);
    store_b32_dev(hbuf + ((t+1)&1)*32768 + es*KH + ga + 2*ep, hpack);
    wait_vm0();                                        // h at coherence point
    __syncthreads();                                   // B4: all threads drained
    if (tid == 0)
      __hip_atomic_store(&flags[t*64 + q], 1, __ATOMIC_RELAXED, __HIP_MEMORY_SCOPE_AGENT);

    // off-critical-path result stores (drained by next step / kernel end)
    if (LAYER == 0){
      *(unsigned int*)&hsOut[(long)(es*KT + t)*KH + ga + 2*ep] = hpack;
    } else {
      if (es < 16)
        *(float2*)&out[(long)(es*KT + t)*KG + ga + 2*ep] = make_float2(hn0, hn1);
      else
        *(float2*)&out[(long)((es-16)*KT + (KT-1-t))*KG + KH + ga + 2*ep] = make_float2(hn0, hn1);
    }
  }
}

// ---------------- orchestration ----------------
extern "C" void kernel_launch(void* const* d_in, const int* in_sizes, int n_in,
                              void* d_out, int out_size, void* d_ws, size_t ws_size,
                              hipStream_t stream)
{
  const float* x  = (const float*)d_in[0];
  const float* w0 = (const float*)d_in[1];
  const float* u0 = (const float*)d_in[2];
  const float* g0 = (const float*)d_in[3];
  const float* b0 = (const float*)d_in[4];
  const float* w1 = (const float*)d_in[5];
  const float* u1 = (const float*)d_in[6];
  const float* g1 = (const float*)d_in[7];
  const float* b1 = (const float*)d_in[8];
  float* out = (float*)d_out;

  char* p = (char*)d_ws;
  auto alloc = [&](size_t n){ char* r = p; p += (n + 255) & ~(size_t)255; return r; };
  unsigned short* xb   = (unsigned short*)alloc((size_t)16*KT*512*2);
  unsigned short* w0b  = (unsigned short*)alloc((size_t)KG*512*2);
  unsigned short* u0b  = (unsigned short*)alloc((size_t)KG*KH*2);
  unsigned short* w1b  = (unsigned short*)alloc((size_t)KG*KG*2);
  unsigned short* u1b  = (unsigned short*)alloc((size_t)KG*KH*2);
  unsigned short* wbuf = (unsigned short*)alloc((size_t)32*KT*KG*2);
  unsigned short* hs0  = (unsigned short*)alloc((size_t)32*KT*KH*2);
  float* part          = (float*)alloc((size_t)125*4096*4);
  float* scsh          = (float*)alloc((size_t)2*KG*4);
  unsigned short* hbuf = (unsigned short*)alloc((size_t)2*2*32*KH*2);
  int* flags           = (int*)alloc((size_t)2*KT*64*4);

  auto cast = [&](const float* s, unsigned short* d, int n){
    int n4 = n >> 2;
    castk<<<(n4+255)/256, 256, 0, stream>>>(s, d, n4);
  };
  cast(x,  xb,  16*KT*512);
  cast(w0, w0b, KG*512);
  cast(u0, u0b, KG*KH);
  cast(w1, w1b, KG*KG);
  cast(u1, u1b, KG*KH);
  hipMemsetAsync(hbuf,  0, (size_t)2*2*32*KH*2, stream);
  hipMemsetAsync(flags, 0, (size_t)2*KT*64*4,  stream);

  // layer 0
  gemm_bn<0,512><<<dim3(16,125), 256, 0, stream>>>(xb, w0b, wbuf);
  bn_partial<<<125,256,0,stream>>>(wbuf, part);
  bn_final<<<8,256,0,stream>>>(part, g0, b0, scsh);
  recur<0><<<64,256,0,stream>>>(u0b, wbuf, scsh, hbuf, flags, hs0, (float*)nullptr);

  // layer 1
  gemm_bn<1,2048><<<dim3(16,125), 256, 0, stream>>>(hs0, w1b, wbuf);
  bn_partial<<<125,256,0,stream>>>(wbuf, part);
  bn_final<<<8,256,0,stream>>>(part, g1, b1, scsh);
  recur<1><<<64,256,0,stream>>>(u1b, wbuf, scsh, hbuf + 2*32*KH, flags + KT*64,
                                (unsigned short*)nullptr, out);
}